// Round 1
// baseline (3679.784 us; speedup 1.0000x reference)
//
#include <hip/hip_runtime.h>

#define HF 128

// ---------- input projection: out[N][128] = x[N][K] @ w[K][128] + b ----------
template<int K>
__global__ __launch_bounds__(256) void proj_kernel(
    const float* __restrict__ x, const float* __restrict__ w,
    const float* __restrict__ b, float* __restrict__ out, int N)
{
  int col = threadIdx.x & (HF - 1);
  int row = (blockIdx.x << 1) + (threadIdx.x >> 7);
  if (row >= N) return;
  const float* xr = x + (size_t)row * K;
  float acc = b[col];
#pragma unroll
  for (int k = 0; k < K; ++k) acc = fmaf(xr[k], w[k * HF + col], acc);
  out[(size_t)row * HF + col] = acc;
}

// ---------- transpose nmat 128x128 matrices: wT[m][j][k] = w[m][k][j] ----------
__global__ void transpose_kernel(const float* __restrict__ w, float* __restrict__ wT, int total)
{
  int idx = blockIdx.x * blockDim.x + threadIdx.x;
  if (idx >= total) return;
  int m = idx >> 14;
  int r = idx & 16383;
  int j = r >> 7, k = r & (HF - 1);
  wT[(m << 14) + (j << 7) + k] = w[(m << 14) + (k << 7) + j];
}

// ---------- CSR build: count ----------
__global__ void count_kernel(const int* __restrict__ dst, int* __restrict__ cnt,
                             int* __restrict__ pos, int E)
{
  int e = blockIdx.x * blockDim.x + threadIdx.x;
  if (e < E) pos[e] = atomicAdd(&cnt[dst[e]], 1);
}

// ---------- 3-phase exclusive scan (in-place on data[0..n-1]) ----------
__global__ __launch_bounds__(1024) void scan_p1(int* __restrict__ data, int* __restrict__ bsum, int n)
{
  __shared__ int s[1024];
  int tid = threadIdx.x;
  int i = blockIdx.x * 1024 + tid;
  int v = (i < n) ? data[i] : 0;
  s[tid] = v;
  __syncthreads();
  for (int off = 1; off < 1024; off <<= 1) {
    int t = (tid >= off) ? s[tid - off] : 0;
    __syncthreads();
    s[tid] += t;
    __syncthreads();
  }
  if (i < n) data[i] = s[tid] - v;  // exclusive within block
  if (tid == 1023) bsum[blockIdx.x] = s[1023];
}

__global__ __launch_bounds__(1024) void scan_p2(int* __restrict__ bsum, int nb)
{
  __shared__ int s[1024];
  int tid = threadIdx.x;
  int v = (tid < nb) ? bsum[tid] : 0;
  s[tid] = v;
  __syncthreads();
  for (int off = 1; off < 1024; off <<= 1) {
    int t = (tid >= off) ? s[tid - off] : 0;
    __syncthreads();
    s[tid] += t;
    __syncthreads();
  }
  if (tid < nb) bsum[tid] = s[tid] - v;  // exclusive block offsets
}

__global__ __launch_bounds__(1024) void scan_p3(int* __restrict__ data, const int* __restrict__ bsum,
                                                int n, int total)
{
  int i = blockIdx.x * 1024 + threadIdx.x;
  if (i < n) data[i] += bsum[blockIdx.x];
  if (i == 0) data[n] = total;
}

// ---------- CSR build: scatter src ids into slots ----------
__global__ void fill_kernel(const int* __restrict__ dst, const int* __restrict__ src,
                            const int* __restrict__ rp, const int* __restrict__ pos,
                            int* __restrict__ colv, int E)
{
  int e = blockIdx.x * blockDim.x + threadIdx.x;
  if (e < E) colv[rp[dst[e]] + pos[e]] = src[e];
}

// ---------- mean aggregation: one wave per destination node ----------
__global__ __launch_bounds__(256) void agg_kernel(
    const float* __restrict__ feat, const int* __restrict__ rp,
    const int* __restrict__ colv, float* __restrict__ out, int ndst)
{
  int gw = (int)((blockIdx.x * blockDim.x + threadIdx.x) >> 6);
  int lane = threadIdx.x & 63;
  int nw = (int)((gridDim.x * blockDim.x) >> 6);
  for (int d = gw; d < ndst; d += nw) {
    int beg = rp[d], end = rp[d + 1];
    float ax = 0.f, ay = 0.f;
    for (int j = beg; j < end; ++j) {
      int s = colv[j];
      const float2 v = *(const float2*)(feat + (size_t)s * HF + lane * 2);
      ax += v.x;
      ay += v.y;
    }
    int dg = end - beg;
    float inv = 1.0f / (float)(dg > 0 ? dg : 1);
    float2 o;
    o.x = ax * inv;
    o.y = ay * inv;
    *(float2*)(out + (size_t)d * HF + lane * 2) = o;
  }
}

// ---------- fused SAGE layer: out = relu(agg @ Wl + bl + x @ Wr) ----------
// block = 256 threads, tile = 32 rows x 128 cols, 4x4 register tile/thread
__global__ __launch_bounds__(256) void sage_kernel(
    const float* __restrict__ agg, const float* __restrict__ x,
    const float* __restrict__ wlT, const float* __restrict__ wrT,
    const float* __restrict__ bl, float* __restrict__ out, int N)
{
  __shared__ float a_s[32][HF];
  __shared__ float x_s[32][HF];
  const int tid = threadIdx.x;
  const int r0 = blockIdx.x * 32;
  for (int idx = tid; idx < 32 * HF; idx += 256) {
    int r = idx >> 7, c = idx & (HF - 1);
    int row = r0 + r;
    float av = 0.f, xv = 0.f;
    if (row < N) {
      av = agg[(size_t)row * HF + c];
      xv = x[(size_t)row * HF + c];
    }
    a_s[r][c] = av;
    x_s[r][c] = xv;
  }
  __syncthreads();

  const int cg = tid & 31;   // col group -> cols cg*4 .. cg*4+3
  const int rg = tid >> 5;   // row group -> rows rg + 8*rr
  const int jc = cg * 4;
  float acc[4][4];
#pragma unroll
  for (int rr = 0; rr < 4; ++rr)
#pragma unroll
    for (int c = 0; c < 4; ++c) acc[rr][c] = 0.f;

  for (int k = 0; k < HF; k += 4) {
    float4 wl[4], wr[4];
#pragma unroll
    for (int c = 0; c < 4; ++c) {
      wl[c] = *(const float4*)(wlT + (size_t)(jc + c) * HF + k);
      wr[c] = *(const float4*)(wrT + (size_t)(jc + c) * HF + k);
    }
#pragma unroll
    for (int rr = 0; rr < 4; ++rr) {
      const float4 a4 = *(const float4*)&a_s[rg + rr * 8][k];
      const float4 x4 = *(const float4*)&x_s[rg + rr * 8][k];
#pragma unroll
      for (int c = 0; c < 4; ++c) {
        float t = acc[rr][c];
        t = fmaf(a4.x, wl[c].x, t);
        t = fmaf(a4.y, wl[c].y, t);
        t = fmaf(a4.z, wl[c].z, t);
        t = fmaf(a4.w, wl[c].w, t);
        t = fmaf(x4.x, wr[c].x, t);
        t = fmaf(x4.y, wr[c].y, t);
        t = fmaf(x4.z, wr[c].z, t);
        t = fmaf(x4.w, wr[c].w, t);
        acc[rr][c] = t;
      }
    }
  }

  const float4 bv = *(const float4*)(bl + jc);
#pragma unroll
  for (int rr = 0; rr < 4; ++rr) {
    int row = r0 + rg + rr * 8;
    if (row < N) {
      float4 o;
      o.x = fmaxf(acc[rr][0] + bv.x, 0.f);
      o.y = fmaxf(acc[rr][1] + bv.y, 0.f);
      o.z = fmaxf(acc[rr][2] + bv.z, 0.f);
      o.w = fmaxf(acc[rr][3] + bv.w, 0.f);
      *(float4*)(out + (size_t)row * HF + jc) = o;
    }
  }
}

extern "C" void kernel_launch(void* const* d_in, const int* in_sizes, int n_in,
                              void* d_out, int out_size, void* d_ws, size_t ws_size,
                              hipStream_t stream)
{
  const float* x_user  = (const float*)d_in[0];
  const float* x_item  = (const float*)d_in[1];
  const float* user_w  = (const float*)d_in[2];
  const float* user_b  = (const float*)d_in[3];
  const float* item_w  = (const float*)d_in[4];
  const float* item_b  = (const float*)d_in[5];
  const float* conv_wl = (const float*)d_in[6];
  const float* conv_bl = (const float*)d_in[7];
  const float* conv_wr = (const float*)d_in[8];
  const int* src_u2i = (const int*)d_in[9];
  const int* dst_u2i = (const int*)d_in[10];
  const int* src_i2u = (const int*)d_in[11];
  const int* dst_i2u = (const int*)d_in[12];

  const int NU = in_sizes[0] / 32;
  const int NI = in_sizes[1] / 64;
  const int E  = in_sizes[9];
  const int L  = in_sizes[6] / (2 * HF * HF);

  float* out_u = (float*)d_out;
  float* out_i = out_u + (size_t)NU * HF;

  // workspace carve-out (256B aligned)
  char* wsb = (char*)d_ws;
  size_t off = 0;
  auto alloc = [&](size_t bytes) -> void* {
    void* p = wsb + off;
    off = (off + bytes + 255) & ~(size_t)255;
    return p;
  };
  float* uA    = (float*)alloc((size_t)NU * HF * 4);
  float* iA    = (float*)alloc((size_t)NI * HF * 4);
  float* agg_u = (float*)alloc((size_t)NU * HF * 4);
  float* agg_i = (float*)alloc((size_t)NI * HF * 4);
  float* wlT   = (float*)alloc((size_t)L * 2 * HF * HF * 4);
  float* wrT   = (float*)alloc((size_t)L * 2 * HF * HF * 4);
  int* rp_i    = (int*)alloc((size_t)(NI + 1) * 4);
  int* rp_u    = (int*)alloc((size_t)(NU + 1) * 4);
  int* pos     = (int*)alloc((size_t)E * 4);
  int* col_u2i = (int*)alloc((size_t)E * 4);
  int* col_i2u = (int*)alloc((size_t)E * 4);
  int* bsum    = (int*)alloc(4096 * 4);
  (void)ws_size; (void)n_in; (void)out_size;

  // 1) input projections (into d_out, consumed by layer 0)
  proj_kernel<32><<<(NU + 1) / 2, 256, 0, stream>>>(x_user, user_w, user_b, out_u, NU);
  proj_kernel<64><<<(NI + 1) / 2, 256, 0, stream>>>(x_item, item_w, item_b, out_i, NI);

  // 2) weight transposes
  {
    int total = L * 2 * HF * HF;
    int g = (total + 255) / 256;
    transpose_kernel<<<g, 256, 0, stream>>>(conv_wl, wlT, total);
    transpose_kernel<<<g, 256, 0, stream>>>(conv_wr, wrT, total);
  }

  // 3) CSR build for both directions (graph reused across layers)
  auto build_csr = [&](const int* dst, const int* srcv, int* rp, int* colv, int n) {
    hipMemsetAsync(rp, 0, (size_t)(n + 1) * sizeof(int), stream);
    int gE = (E + 255) / 256;
    count_kernel<<<gE, 256, 0, stream>>>(dst, rp, pos, E);
    int nb = (n + 1023) / 1024;
    scan_p1<<<nb, 1024, 0, stream>>>(rp, bsum, n);
    scan_p2<<<1, 1024, 0, stream>>>(bsum, nb);
    scan_p3<<<nb, 1024, 0, stream>>>(rp, bsum, n, E);
    fill_kernel<<<gE, 256, 0, stream>>>(dst, srcv, rp, pos, colv, E);
  };
  build_csr(dst_u2i, src_u2i, rp_i, col_u2i, NI);
  build_csr(dst_i2u, src_i2u, rp_u, col_i2u, NU);

  // 4) layers: even layer reads d_out, writes ws; odd layer reads ws, writes d_out
  const float* cu = out_u;
  const float* ci = out_i;
  for (int l = 0; l < L; ++l) {
    float* nu = (l & 1) ? out_u : uA;
    float* ni = (l & 1) ? out_i : iA;

    agg_kernel<<<(NI + 3) / 4, 256, 0, stream>>>(cu, rp_i, col_u2i, agg_i, NI);
    agg_kernel<<<(NU + 3) / 4, 256, 0, stream>>>(ci, rp_u, col_i2u, agg_u, NU);

    const float* wl0 = wlT + (size_t)(l * 2 + 0) * HF * HF;
    const float* wr0 = wrT + (size_t)(l * 2 + 0) * HF * HF;
    const float* bl0 = conv_bl + (size_t)(l * 2 + 0) * HF;
    const float* wl1 = wlT + (size_t)(l * 2 + 1) * HF * HF;
    const float* wr1 = wrT + (size_t)(l * 2 + 1) * HF * HF;
    const float* bl1 = conv_bl + (size_t)(l * 2 + 1) * HF;

    sage_kernel<<<(NI + 31) / 32, 256, 0, stream>>>(agg_i, ci, wl0, wr0, bl0, ni, NI);
    sage_kernel<<<(NU + 31) / 32, 256, 0, stream>>>(agg_u, cu, wl1, wr1, bl1, nu, NU);

    cu = nu;
    ci = ni;
  }
}

// Round 3
// 1577.709 us; speedup vs baseline: 2.3324x; 2.3324x over previous
//
#include <hip/hip_runtime.h>

#define HF 128

// ---------- input projection v2: out[N][128] = x[N][K] @ w[K][128] + b ----------
// block = 256 threads, 64 rows/block; weights + x rows staged in LDS.
template<int K>
__global__ __launch_bounds__(256) void proj_kernel(
    const float* __restrict__ x, const float* __restrict__ w,
    const float* __restrict__ b, float* __restrict__ out, int N)
{
  __shared__ float w_s[K][HF];
  __shared__ float x_s[64][K];
  const int tid = threadIdx.x;
  const int r0 = blockIdx.x * 64;

  // stage weights (K*32 float4)
  for (int idx = tid; idx < K * (HF / 4); idx += 256) {
    int k = idx >> 5, c4 = idx & 31;
    *(float4*)&w_s[k][c4 * 4] = *(const float4*)(w + (size_t)k * HF + c4 * 4);
  }
  // stage x rows (64*K/4 float4)
  for (int idx = tid; idx < 64 * (K / 4); idx += 256) {
    int r = idx / (K / 4), c4 = idx % (K / 4);
    int row = r0 + r;
    float4 v = {0.f, 0.f, 0.f, 0.f};
    if (row < N) v = *(const float4*)(x + (size_t)row * K + c4 * 4);
    *(float4*)&x_s[r][c4 * 4] = v;
  }
  __syncthreads();

  const int cg = tid & 31;
  const int rg = tid >> 5;
  const int jc = cg * 4;
  const float4 bv = *(const float4*)(b + jc);
  float acc[8][4];
#pragma unroll
  for (int rr = 0; rr < 8; ++rr) {
    acc[rr][0] = bv.x; acc[rr][1] = bv.y; acc[rr][2] = bv.z; acc[rr][3] = bv.w;
  }

  for (int k = 0; k < K; k += 4) {
    float4 wv[4];
#pragma unroll
    for (int t = 0; t < 4; ++t) wv[t] = *(const float4*)&w_s[k + t][jc];
#pragma unroll
    for (int rr = 0; rr < 8; ++rr) {
      const float4 x4 = *(const float4*)&x_s[rg * 8 + rr][k];
      float xa[4] = {x4.x, x4.y, x4.z, x4.w};
#pragma unroll
      for (int t = 0; t < 4; ++t) {
        acc[rr][0] = fmaf(xa[t], wv[t].x, acc[rr][0]);
        acc[rr][1] = fmaf(xa[t], wv[t].y, acc[rr][1]);
        acc[rr][2] = fmaf(xa[t], wv[t].z, acc[rr][2]);
        acc[rr][3] = fmaf(xa[t], wv[t].w, acc[rr][3]);
      }
    }
  }

#pragma unroll
  for (int rr = 0; rr < 8; ++rr) {
    int row = r0 + rg * 8 + rr;
    if (row < N) {
      float4 o = {acc[rr][0], acc[rr][1], acc[rr][2], acc[rr][3]};
      *(float4*)(out + (size_t)row * HF + jc) = o;
    }
  }
}

// ---------- CSR build: count ----------
__global__ void count_kernel(const int* __restrict__ dst, int* __restrict__ cnt,
                             int* __restrict__ pos, int E)
{
  int e = blockIdx.x * blockDim.x + threadIdx.x;
  if (e < E) pos[e] = atomicAdd(&cnt[dst[e]], 1);
}

// ---------- 3-phase exclusive scan ----------
__global__ __launch_bounds__(1024) void scan_p1(int* __restrict__ data, int* __restrict__ bsum, int n)
{
  __shared__ int s[1024];
  int tid = threadIdx.x;
  int i = blockIdx.x * 1024 + tid;
  int v = (i < n) ? data[i] : 0;
  s[tid] = v;
  __syncthreads();
  for (int off = 1; off < 1024; off <<= 1) {
    int t = (tid >= off) ? s[tid - off] : 0;
    __syncthreads();
    s[tid] += t;
    __syncthreads();
  }
  if (i < n) data[i] = s[tid] - v;
  if (tid == 1023) bsum[blockIdx.x] = s[1023];
}

__global__ __launch_bounds__(1024) void scan_p2(int* __restrict__ bsum, int nb)
{
  __shared__ int s[1024];
  int tid = threadIdx.x;
  int v = (tid < nb) ? bsum[tid] : 0;
  s[tid] = v;
  __syncthreads();
  for (int off = 1; off < 1024; off <<= 1) {
    int t = (tid >= off) ? s[tid - off] : 0;
    __syncthreads();
    s[tid] += t;
    __syncthreads();
  }
  if (tid < nb) bsum[tid] = s[tid] - v;
}

__global__ __launch_bounds__(1024) void scan_p3(int* __restrict__ data, const int* __restrict__ bsum,
                                                int n, int total)
{
  int i = blockIdx.x * 1024 + threadIdx.x;
  if (i < n) data[i] += bsum[blockIdx.x];
  if (i == 0) data[n] = total;
}

// ---------- CSR build: scatter ----------
__global__ void fill_kernel(const int* __restrict__ dst, const int* __restrict__ src,
                            const int* __restrict__ rp, const int* __restrict__ pos,
                            int* __restrict__ colv, int E)
{
  int e = blockIdx.x * blockDim.x + threadIdx.x;
  if (e < E) colv[rp[dst[e]] + pos[e]] = src[e];
}

// ---------- mean aggregation: one wave per destination node ----------
__global__ __launch_bounds__(256) void agg_kernel(
    const float* __restrict__ feat, const int* __restrict__ rp,
    const int* __restrict__ colv, float* __restrict__ out, int ndst)
{
  int gw = (int)((blockIdx.x * blockDim.x + threadIdx.x) >> 6);
  int lane = threadIdx.x & 63;
  int nw = (int)((gridDim.x * blockDim.x) >> 6);
  for (int d = gw; d < ndst; d += nw) {
    int beg = rp[d], end = rp[d + 1];
    float ax = 0.f, ay = 0.f;
    for (int j = beg; j < end; ++j) {
      int s = colv[j];
      const float2 v = *(const float2*)(feat + (size_t)s * HF + lane * 2);
      ax += v.x;
      ay += v.y;
    }
    int dg = end - beg;
    float inv = 1.0f / (float)(dg > 0 ? dg : 1);
    float2 o;
    o.x = ax * inv;
    o.y = ay * inv;
    *(float2*)(out + (size_t)d * HF + lane * 2) = o;
  }
}

// ---------- fused SAGE layer v2: out = relu(agg @ Wl + bl + x @ Wr) ----------
// block = 256 threads, tile = 64 rows x 128 cols; weights LDS-staged in 16-k
// chunks (fixes R1's L2-latency bound: VALUBusy was 17%). 80 KB LDS -> 2 blk/CU.
#define KC 16
__global__ __launch_bounds__(256) void sage_kernel(
    const float* __restrict__ agg, const float* __restrict__ x,
    const float* __restrict__ wl, const float* __restrict__ wr,
    const float* __restrict__ bl, float* __restrict__ out, int N)
{
  __shared__ float a_s[64][HF];
  __shared__ float x_s[64][HF];
  __shared__ float wl_s[KC][HF];
  __shared__ float wr_s[KC][HF];
  const int tid = threadIdx.x;
  const int r0 = blockIdx.x * 64;

  // stage 64 rows of agg & x (2048 float4 each)
  for (int idx = tid; idx < 64 * (HF / 4); idx += 256) {
    int r = idx >> 5, c4 = idx & 31;
    int row = r0 + r;
    float4 av = {0.f, 0.f, 0.f, 0.f}, xv = {0.f, 0.f, 0.f, 0.f};
    if (row < N) {
      av = *(const float4*)(agg + (size_t)row * HF + c4 * 4);
      xv = *(const float4*)(x + (size_t)row * HF + c4 * 4);
    }
    *(float4*)&a_s[r][c4 * 4] = av;
    *(float4*)&x_s[r][c4 * 4] = xv;
  }

  const int cg = tid & 31;
  const int rg = tid >> 5;
  const int jc = cg * 4;
  float acc[8][4];
#pragma unroll
  for (int rr = 0; rr < 8; ++rr)
#pragma unroll
    for (int c = 0; c < 4; ++c) acc[rr][c] = 0.f;

  for (int k0 = 0; k0 < HF; k0 += KC) {
    __syncthreads();  // rows staged (iter 0) / previous chunk consumed
    for (int idx = tid; idx < KC * (HF / 4); idx += 256) {
      int kk = idx >> 5, c4 = idx & 31;
      *(float4*)&wl_s[kk][c4 * 4] = *(const float4*)(wl + (size_t)(k0 + kk) * HF + c4 * 4);
      *(float4*)&wr_s[kk][c4 * 4] = *(const float4*)(wr + (size_t)(k0 + kk) * HF + c4 * 4);
    }
    __syncthreads();

    for (int kk = 0; kk < KC; kk += 4) {
      float4 wlv[4], wrv[4];
#pragma unroll
      for (int t = 0; t < 4; ++t) {
        wlv[t] = *(const float4*)&wl_s[kk + t][jc];
        wrv[t] = *(const float4*)&wr_s[kk + t][jc];
      }
#pragma unroll
      for (int rr = 0; rr < 8; ++rr) {
        const float4 a4 = *(const float4*)&a_s[rg * 8 + rr][k0 + kk];
        const float4 x4 = *(const float4*)&x_s[rg * 8 + rr][k0 + kk];
        float aa[4] = {a4.x, a4.y, a4.z, a4.w};
        float xa[4] = {x4.x, x4.y, x4.z, x4.w};
#pragma unroll
        for (int t = 0; t < 4; ++t) {
          acc[rr][0] = fmaf(aa[t], wlv[t].x, fmaf(xa[t], wrv[t].x, acc[rr][0]));
          acc[rr][1] = fmaf(aa[t], wlv[t].y, fmaf(xa[t], wrv[t].y, acc[rr][1]));
          acc[rr][2] = fmaf(aa[t], wlv[t].z, fmaf(xa[t], wrv[t].z, acc[rr][2]));
          acc[rr][3] = fmaf(aa[t], wlv[t].w, fmaf(xa[t], wrv[t].w, acc[rr][3]));
        }
      }
    }
  }

  const float4 bv = *(const float4*)(bl + jc);
#pragma unroll
  for (int rr = 0; rr < 8; ++rr) {
    int row = r0 + rg * 8 + rr;
    if (row < N) {
      float4 o;
      o.x = fmaxf(acc[rr][0] + bv.x, 0.f);
      o.y = fmaxf(acc[rr][1] + bv.y, 0.f);
      o.z = fmaxf(acc[rr][2] + bv.z, 0.f);
      o.w = fmaxf(acc[rr][3] + bv.w, 0.f);
      *(float4*)(out + (size_t)row * HF + jc) = o;
    }
  }
}

extern "C" void kernel_launch(void* const* d_in, const int* in_sizes, int n_in,
                              void* d_out, int out_size, void* d_ws, size_t ws_size,
                              hipStream_t stream)
{
  const float* x_user  = (const float*)d_in[0];
  const float* x_item  = (const float*)d_in[1];
  const float* user_w  = (const float*)d_in[2];
  const float* user_b  = (const float*)d_in[3];
  const float* item_w  = (const float*)d_in[4];
  const float* item_b  = (const float*)d_in[5];
  const float* conv_wl = (const float*)d_in[6];
  const float* conv_bl = (const float*)d_in[7];
  const float* conv_wr = (const float*)d_in[8];
  const int* src_u2i = (const int*)d_in[9];
  const int* dst_u2i = (const int*)d_in[10];
  const int* src_i2u = (const int*)d_in[11];
  const int* dst_i2u = (const int*)d_in[12];

  const int NU = in_sizes[0] / 32;
  const int NI = in_sizes[1] / 64;
  const int E  = in_sizes[9];
  const int L  = in_sizes[6] / (2 * HF * HF);

  float* out_u = (float*)d_out;
  float* out_i = out_u + (size_t)NU * HF;

  char* wsb = (char*)d_ws;
  size_t off = 0;
  auto alloc = [&](size_t bytes) -> void* {
    void* p = wsb + off;
    off = (off + bytes + 255) & ~(size_t)255;
    return p;
  };
  float* uA    = (float*)alloc((size_t)NU * HF * 4);
  float* iA    = (float*)alloc((size_t)NI * HF * 4);
  float* agg_u = (float*)alloc((size_t)NU * HF * 4);
  float* agg_i = (float*)alloc((size_t)NI * HF * 4);
  int* rp_i    = (int*)alloc((size_t)(NI + 1) * 4);
  int* rp_u    = (int*)alloc((size_t)(NU + 1) * 4);
  int* pos     = (int*)alloc((size_t)E * 4);
  int* col_u2i = (int*)alloc((size_t)E * 4);
  int* col_i2u = (int*)alloc((size_t)E * 4);
  int* bsum    = (int*)alloc(4096 * 4);
  (void)ws_size; (void)n_in; (void)out_size;

  // 1) input projections (into d_out, consumed by layer 0)
  proj_kernel<32><<<(NU + 63) / 64, 256, 0, stream>>>(x_user, user_w, user_b, out_u, NU);
  proj_kernel<64><<<(NI + 63) / 64, 256, 0, stream>>>(x_item, item_w, item_b, out_i, NI);

  // 2) CSR build for both directions (graph reused across layers)
  auto build_csr = [&](const int* dst, const int* srcv, int* rp, int* colv, int n) {
    (void)hipMemsetAsync(rp, 0, (size_t)(n + 1) * sizeof(int), stream);
    int gE = (E + 255) / 256;
    count_kernel<<<gE, 256, 0, stream>>>(dst, rp, pos, E);
    int nb = (n + 1023) / 1024;
    scan_p1<<<nb, 1024, 0, stream>>>(rp, bsum, n);
    scan_p2<<<1, 1024, 0, stream>>>(bsum, nb);
    scan_p3<<<nb, 1024, 0, stream>>>(rp, bsum, n, E);
    fill_kernel<<<gE, 256, 0, stream>>>(dst, srcv, rp, pos, colv, E);
  };
  build_csr(dst_u2i, src_u2i, rp_i, col_u2i, NI);
  build_csr(dst_i2u, src_i2u, rp_u, col_i2u, NU);

  // 3) layers
  const float* cu = out_u;
  const float* ci = out_i;
  for (int l = 0; l < L; ++l) {
    float* nu = (l & 1) ? out_u : uA;
    float* ni = (l & 1) ? out_i : iA;

    agg_kernel<<<(NI + 3) / 4, 256, 0, stream>>>(cu, rp_i, col_u2i, agg_i, NI);
    agg_kernel<<<(NU + 3) / 4, 256, 0, stream>>>(ci, rp_u, col_i2u, agg_u, NU);

    const float* wl0 = conv_wl + (size_t)(l * 2 + 0) * HF * HF;
    const float* wr0 = conv_wr + (size_t)(l * 2 + 0) * HF * HF;
    const float* bl0 = conv_bl + (size_t)(l * 2 + 0) * HF;
    const float* wl1 = conv_wl + (size_t)(l * 2 + 1) * HF * HF;
    const float* wr1 = conv_wr + (size_t)(l * 2 + 1) * HF * HF;
    const float* bl1 = conv_bl + (size_t)(l * 2 + 1) * HF;

    sage_kernel<<<(NI + 63) / 64, 256, 0, stream>>>(agg_i, ci, wl0, wr0, bl0, ni, NI);
    sage_kernel<<<(NU + 63) / 64, 256, 0, stream>>>(agg_u, cu, wl1, wr1, bl1, nu, NU);

    cu = nu;
    ci = ni;
  }
}

// Round 4
// 1386.633 us; speedup vs baseline: 2.6538x; 1.1378x over previous
//
#include <hip/hip_runtime.h>

#define HF 128

typedef __attribute__((ext_vector_type(8))) short short8;
typedef __attribute__((ext_vector_type(16))) float f32x16;

__device__ inline unsigned short f2bf(float x) {
  unsigned u = __float_as_uint(x);
  unsigned r = u + 0x7fffu + ((u >> 16) & 1u);
  return (unsigned short)(r >> 16);
}

// split 8 fp32 -> bf16 hi (truncate) + bf16 lo (residual, RNE)
__device__ inline void split8(const float4 fa, const float4 fb, short8& hi, short8& lo)
{
  float f[8] = {fa.x, fa.y, fa.z, fa.w, fb.x, fb.y, fb.z, fb.w};
  union { unsigned int u[4]; short8 s; } H, L;
#pragma unroll
  for (int p = 0; p < 4; ++p) {
    unsigned u0 = __float_as_uint(f[2 * p]);
    unsigned u1 = __float_as_uint(f[2 * p + 1]);
    H.u[p] = (u0 >> 16) | (u1 & 0xffff0000u);
    float l0 = f[2 * p]     - __uint_as_float(u0 & 0xffff0000u);
    float l1 = f[2 * p + 1] - __uint_as_float(u1 & 0xffff0000u);
    L.u[p] = (unsigned)f2bf(l0) | ((unsigned)f2bf(l1) << 16);
  }
  hi = H.s; lo = L.s;
}

// ---------- input projection: out[N][128] = x[N][K] @ w[K][128] + b ----------
template<int K>
__global__ __launch_bounds__(256) void proj_kernel(
    const float* __restrict__ x, const float* __restrict__ w,
    const float* __restrict__ b, float* __restrict__ out, int N)
{
  __shared__ float w_s[K][HF];
  __shared__ float x_s[64][K];
  const int tid = threadIdx.x;
  const int r0 = blockIdx.x * 64;

  for (int idx = tid; idx < K * (HF / 4); idx += 256) {
    int k = idx >> 5, c4 = idx & 31;
    *(float4*)&w_s[k][c4 * 4] = *(const float4*)(w + (size_t)k * HF + c4 * 4);
  }
  for (int idx = tid; idx < 64 * (K / 4); idx += 256) {
    int r = idx / (K / 4), c4 = idx % (K / 4);
    int row = r0 + r;
    float4 v = {0.f, 0.f, 0.f, 0.f};
    if (row < N) v = *(const float4*)(x + (size_t)row * K + c4 * 4);
    *(float4*)&x_s[r][c4 * 4] = v;
  }
  __syncthreads();

  const int cg = tid & 31;
  const int rg = tid >> 5;
  const int jc = cg * 4;
  const float4 bv = *(const float4*)(b + jc);
  float acc[8][4];
#pragma unroll
  for (int rr = 0; rr < 8; ++rr) {
    acc[rr][0] = bv.x; acc[rr][1] = bv.y; acc[rr][2] = bv.z; acc[rr][3] = bv.w;
  }

  for (int k = 0; k < K; k += 4) {
    float4 wv[4];
#pragma unroll
    for (int t = 0; t < 4; ++t) wv[t] = *(const float4*)&w_s[k + t][jc];
#pragma unroll
    for (int rr = 0; rr < 8; ++rr) {
      const float4 x4 = *(const float4*)&x_s[rg * 8 + rr][k];
      float xa[4] = {x4.x, x4.y, x4.z, x4.w};
#pragma unroll
      for (int t = 0; t < 4; ++t) {
        acc[rr][0] = fmaf(xa[t], wv[t].x, acc[rr][0]);
        acc[rr][1] = fmaf(xa[t], wv[t].y, acc[rr][1]);
        acc[rr][2] = fmaf(xa[t], wv[t].z, acc[rr][2]);
        acc[rr][3] = fmaf(xa[t], wv[t].w, acc[rr][3]);
      }
    }
  }

#pragma unroll
  for (int rr = 0; rr < 8; ++rr) {
    int row = r0 + rg * 8 + rr;
    if (row < N) {
      float4 o = {acc[rr][0], acc[rr][1], acc[rr][2], acc[rr][3]};
      *(float4*)(out + (size_t)row * HF + jc) = o;
    }
  }
}

// ---------- CSR build ----------
__global__ void count_kernel(const int* __restrict__ dst, int* __restrict__ cnt,
                             int* __restrict__ pos, int E)
{
  int e = blockIdx.x * blockDim.x + threadIdx.x;
  if (e < E) pos[e] = atomicAdd(&cnt[dst[e]], 1);
}

__global__ __launch_bounds__(1024) void scan_p1(int* __restrict__ data, int* __restrict__ bsum, int n)
{
  __shared__ int s[1024];
  int tid = threadIdx.x;
  int i = blockIdx.x * 1024 + tid;
  int v = (i < n) ? data[i] : 0;
  s[tid] = v;
  __syncthreads();
  for (int off = 1; off < 1024; off <<= 1) {
    int t = (tid >= off) ? s[tid - off] : 0;
    __syncthreads();
    s[tid] += t;
    __syncthreads();
  }
  if (i < n) data[i] = s[tid] - v;
  if (tid == 1023) bsum[blockIdx.x] = s[1023];
}

__global__ __launch_bounds__(1024) void scan_p2(int* __restrict__ bsum, int nb)
{
  __shared__ int s[1024];
  int tid = threadIdx.x;
  int v = (tid < nb) ? bsum[tid] : 0;
  s[tid] = v;
  __syncthreads();
  for (int off = 1; off < 1024; off <<= 1) {
    int t = (tid >= off) ? s[tid - off] : 0;
    __syncthreads();
    s[tid] += t;
    __syncthreads();
  }
  if (tid < nb) bsum[tid] = s[tid] - v;
}

__global__ __launch_bounds__(1024) void scan_p3(int* __restrict__ data, const int* __restrict__ bsum,
                                                int n, int total)
{
  int i = blockIdx.x * 1024 + threadIdx.x;
  if (i < n) data[i] += bsum[blockIdx.x];
  if (i == 0) data[n] = total;
}

__global__ void fill_kernel(const int* __restrict__ dst, const int* __restrict__ src,
                            const int* __restrict__ rp, const int* __restrict__ pos,
                            int* __restrict__ colv, int E)
{
  int e = blockIdx.x * blockDim.x + threadIdx.x;
  if (e < E) colv[rp[dst[e]] + pos[e]] = src[e];
}

// ---------- mean aggregation: one wave per destination node ----------
__global__ __launch_bounds__(256) void agg_kernel(
    const float* __restrict__ feat, const int* __restrict__ rp,
    const int* __restrict__ colv, float* __restrict__ out, int ndst)
{
  int gw = (int)((blockIdx.x * blockDim.x + threadIdx.x) >> 6);
  int lane = threadIdx.x & 63;
  int nw = (int)((gridDim.x * blockDim.x) >> 6);
  for (int d = gw; d < ndst; d += nw) {
    int beg = rp[d], end = rp[d + 1];
    float ax = 0.f, ay = 0.f;
    for (int j = beg; j < end; ++j) {
      int s = colv[j];
      const float2 v = *(const float2*)(feat + (size_t)s * HF + lane * 2);
      ax += v.x;
      ay += v.y;
    }
    int dg = end - beg;
    float inv = 1.0f / (float)(dg > 0 ? dg : 1);
    float2 o;
    o.x = ax * inv;
    o.y = ay * inv;
    *(float2*)(out + (size_t)d * HF + lane * 2) = o;
  }
}

// ---------- weight pack: W=[Wl;Wr] (256x128) -> bf16 hi/lo MFMA-frag tiles ----
// layout: bpack + combo*131072 + kc*16384 + part*8192 + kt*4096 + ct*1024 + lane*16
// frag (32x32x16 B operand): lane l: col = ct*32 + (l&31), k = kc*32+kt*16+(l>>5)*8+j
__global__ void wpack_kernel(const float* __restrict__ wl, const float* __restrict__ wr,
                             unsigned char* __restrict__ bpack, int ncombo)
{
  int t = blockIdx.x * 256 + threadIdx.x;
  int total = ncombo << 12;
  if (t >= total) return;
  int lane = t & 63;
  int ct = (t >> 6) & 3;
  int kt = (t >> 8) & 1;
  int kc = (t >> 9) & 7;
  int combo = t >> 12;
  const float* WL = wl + (size_t)combo * HF * HF;
  const float* WR = wr + (size_t)combo * HF * HF;
  int col = ct * 32 + (lane & 31);
  int kbase = kc * 32 + kt * 16 + (lane >> 5) * 8;
  float f[8];
#pragma unroll
  for (int j = 0; j < 8; ++j) {
    int k = kbase + j;
    f[j] = (k < HF) ? WL[(size_t)k * HF + col] : WR[(size_t)(k - HF) * HF + col];
  }
  unsigned int hi[4], lo[4];
#pragma unroll
  for (int p = 0; p < 4; ++p) {
    unsigned u0 = __float_as_uint(f[2 * p]);
    unsigned u1 = __float_as_uint(f[2 * p + 1]);
    hi[p] = (u0 >> 16) | (u1 & 0xffff0000u);
    float l0 = f[2 * p]     - __uint_as_float(u0 & 0xffff0000u);
    float l1 = f[2 * p + 1] - __uint_as_float(u1 & 0xffff0000u);
    lo[p] = (unsigned)f2bf(l0) | ((unsigned)f2bf(l1) << 16);
  }
  size_t base = (size_t)combo * 131072 + kc * 16384 + kt * 4096 + ct * 1024 + lane * 16;
  uint4 h = {hi[0], hi[1], hi[2], hi[3]};
  uint4 l = {lo[0], lo[1], lo[2], lo[3]};
  *(uint4*)(bpack + base) = h;
  *(uint4*)(bpack + base + 8192) = l;
}

// ---------- fused SAGE layer (MFMA split-3): out = relu([agg|x] @ [Wl;Wr] + b)
// block 256 = 4 waves; tile 128 rows x 128 cols; wave = 64x64 (2x2 32x32 tiles)
// K=256 in 8 chunks of 32 (kc 0..3: agg, 4..7: x). A fp32 in LDS, XOR-swizzled,
// split to bf16 hi/lo on the fly; B pre-packed bf16 hi/lo frags, linear LDS.
__global__ __launch_bounds__(256, 3) void sage_mfma(
    const float* __restrict__ agg, const float* __restrict__ x,
    const unsigned char* __restrict__ bpk, const float* __restrict__ bias,
    float* __restrict__ out, int N)
{
  __shared__ float4 a_s4[1024];          // 128 rows x 8 chunks (16B), swizzled
  __shared__ uint4 b_s4[1024];           // hi 8KB + lo 8KB, frag-linear
  const int tid = threadIdx.x;
  const int lane = tid & 63;
  const int w = tid >> 6;
  const int wr_ = w >> 1;                // wave row group (0..1) -> rows wr_*64
  const int wc  = w & 1;                 // wave col group (0..1) -> cols wc*64
  const int r0 = blockIdx.x * 128;

  f32x16 acc[2][2];
#pragma unroll
  for (int a = 0; a < 2; ++a)
#pragma unroll
    for (int b = 0; b < 2; ++b)
#pragma unroll
      for (int i = 0; i < 16; ++i) acc[a][b][i] = 0.f;

  for (int kc = 0; kc < 8; ++kc) {
    if (kc) __syncthreads();
    // stage A: 128 rows x 32 k fp32 (1024 float4), swizzle chunk ^= row&7
    const float* srcp = (kc < 4) ? agg : x;
    const int colbase = (kc & 3) * 32;
#pragma unroll
    for (int i = 0; i < 4; ++i) {
      int idx = i * 256 + tid;
      int r = idx >> 3, c = idx & 7;
      int grow = r0 + r;
      float4 v = {0.f, 0.f, 0.f, 0.f};
      if (grow < N) v = *(const float4*)(srcp + (size_t)grow * HF + colbase + c * 4);
      a_s4[r * 8 + (c ^ (r & 7))] = v;
    }
    // stage B: 16KB of this k-chunk's packed frags, linear
    const uint4* gb = (const uint4*)(bpk + (size_t)kc * 16384);
#pragma unroll
    for (int i = 0; i < 4; ++i) {
      int idx = i * 256 + tid;
      b_s4[idx] = gb[idx];
    }
    __syncthreads();

#pragma unroll
    for (int kt = 0; kt < 2; ++kt) {
      // build A hi/lo frags for 2 row tiles
      short8 ahi[2], alo[2];
#pragma unroll
      for (int rt = 0; rt < 2; ++rt) {
        int row_l = wr_ * 64 + rt * 32 + (lane & 31);
        int c0 = kt * 4 + (lane >> 5) * 2;
        float4 fa = a_s4[row_l * 8 + (c0 ^ (row_l & 7))];
        float4 fb = a_s4[row_l * 8 + ((c0 + 1) ^ (row_l & 7))];
        split8(fa, fb, ahi[rt], alo[rt]);
      }
      // read B hi/lo frags for 2 col tiles
      union { uint4 u; short8 s; } bhi[2], blo[2];
#pragma unroll
      for (int ctl = 0; ctl < 2; ++ctl) {
        int ct = wc * 2 + ctl;
        int fi = kt * 256 + ct * 64 + lane;   // uint4 index (4096B = 256 uint4 per kt)
        bhi[ctl].u = b_s4[fi];
        blo[ctl].u = b_s4[512 + fi];          // lo half starts at 8192B
      }
#pragma unroll
      for (int rt = 0; rt < 2; ++rt)
#pragma unroll
        for (int ctl = 0; ctl < 2; ++ctl) {
          acc[rt][ctl] = __builtin_amdgcn_mfma_f32_32x32x16_bf16(ahi[rt], bhi[ctl].s, acc[rt][ctl], 0, 0, 0);
          acc[rt][ctl] = __builtin_amdgcn_mfma_f32_32x32x16_bf16(ahi[rt], blo[ctl].s, acc[rt][ctl], 0, 0, 0);
          acc[rt][ctl] = __builtin_amdgcn_mfma_f32_32x32x16_bf16(alo[rt], bhi[ctl].s, acc[rt][ctl], 0, 0, 0);
        }
    }
  }

  // epilogue: bias + relu. C/D layout: col=lane&31, row=(reg&3)+8*(reg>>2)+4*(lane>>5)
#pragma unroll
  for (int ctl = 0; ctl < 2; ++ctl) {
    int gcol = wc * 64 + ctl * 32 + (lane & 31);
    float bv = bias[gcol];
#pragma unroll
    for (int rt = 0; rt < 2; ++rt) {
#pragma unroll
      for (int reg = 0; reg < 16; ++reg) {
        int row_l = (reg & 3) + 8 * (reg >> 2) + 4 * (lane >> 5);
        int grow = r0 + wr_ * 64 + rt * 32 + row_l;
        if (grow < N) {
          float v = acc[rt][ctl][reg] + bv;
          out[(size_t)grow * HF + gcol] = fmaxf(v, 0.f);
        }
      }
    }
  }
}

extern "C" void kernel_launch(void* const* d_in, const int* in_sizes, int n_in,
                              void* d_out, int out_size, void* d_ws, size_t ws_size,
                              hipStream_t stream)
{
  const float* x_user  = (const float*)d_in[0];
  const float* x_item  = (const float*)d_in[1];
  const float* user_w  = (const float*)d_in[2];
  const float* user_b  = (const float*)d_in[3];
  const float* item_w  = (const float*)d_in[4];
  const float* item_b  = (const float*)d_in[5];
  const float* conv_wl = (const float*)d_in[6];
  const float* conv_bl = (const float*)d_in[7];
  const float* conv_wr = (const float*)d_in[8];
  const int* src_u2i = (const int*)d_in[9];
  const int* dst_u2i = (const int*)d_in[10];
  const int* src_i2u = (const int*)d_in[11];
  const int* dst_i2u = (const int*)d_in[12];

  const int NU = in_sizes[0] / 32;
  const int NI = in_sizes[1] / 64;
  const int E  = in_sizes[9];
  const int L  = in_sizes[6] / (2 * HF * HF);

  float* out_u = (float*)d_out;
  float* out_i = out_u + (size_t)NU * HF;

  char* wsb = (char*)d_ws;
  size_t off = 0;
  auto alloc = [&](size_t bytes) -> void* {
    void* p = wsb + off;
    off = (off + bytes + 255) & ~(size_t)255;
    return p;
  };
  float* uA    = (float*)alloc((size_t)NU * HF * 4);
  float* iA    = (float*)alloc((size_t)NI * HF * 4);
  float* agg_u = (float*)alloc((size_t)NU * HF * 4);
  float* agg_i = (float*)alloc((size_t)NI * HF * 4);
  int* rp_i    = (int*)alloc((size_t)(NI + 1) * 4);
  int* rp_u    = (int*)alloc((size_t)(NU + 1) * 4);
  int* pos     = (int*)alloc((size_t)E * 4);
  int* col_u2i = (int*)alloc((size_t)E * 4);
  int* col_i2u = (int*)alloc((size_t)E * 4);
  int* bsum    = (int*)alloc(4096 * 4);
  unsigned char* bpack = (unsigned char*)alloc((size_t)(2 * L) * 131072);
  (void)ws_size; (void)n_in; (void)out_size;

  // 1) input projections (into d_out, consumed by layer 0)
  proj_kernel<32><<<(NU + 63) / 64, 256, 0, stream>>>(x_user, user_w, user_b, out_u, NU);
  proj_kernel<64><<<(NI + 63) / 64, 256, 0, stream>>>(x_item, item_w, item_b, out_i, NI);

  // 2) weight packing (once; 2L combos)
  {
    int total = (2 * L) << 12;
    wpack_kernel<<<(total + 255) / 256, 256, 0, stream>>>(conv_wl, conv_wr, bpack, 2 * L);
  }

  // 3) CSR build for both directions (graph reused across layers)
  auto build_csr = [&](const int* dst, const int* srcv, int* rp, int* colv, int n) {
    (void)hipMemsetAsync(rp, 0, (size_t)(n + 1) * sizeof(int), stream);
    int gE = (E + 255) / 256;
    count_kernel<<<gE, 256, 0, stream>>>(dst, rp, pos, E);
    int nb = (n + 1023) / 1024;
    scan_p1<<<nb, 1024, 0, stream>>>(rp, bsum, n);
    scan_p2<<<1, 1024, 0, stream>>>(bsum, nb);
    scan_p3<<<nb, 1024, 0, stream>>>(rp, bsum, n, E);
    fill_kernel<<<gE, 256, 0, stream>>>(dst, srcv, rp, pos, colv, E);
  };
  build_csr(dst_u2i, src_u2i, rp_i, col_u2i, NI);
  build_csr(dst_i2u, src_i2u, rp_u, col_i2u, NU);

  // 4) layers
  const float* cu = out_u;
  const float* ci = out_i;
  for (int l = 0; l < L; ++l) {
    float* nu = (l & 1) ? out_u : uA;
    float* ni = (l & 1) ? out_i : iA;

    agg_kernel<<<(NI + 3) / 4, 256, 0, stream>>>(cu, rp_i, col_u2i, agg_i, NI);
    agg_kernel<<<(NU + 3) / 4, 256, 0, stream>>>(ci, rp_u, col_i2u, agg_u, NU);

    const unsigned char* bp0 = bpack + (size_t)(l * 2 + 0) * 131072;
    const unsigned char* bp1 = bpack + (size_t)(l * 2 + 1) * 131072;
    const float* bl0 = conv_bl + (size_t)(l * 2 + 0) * HF;
    const float* bl1 = conv_bl + (size_t)(l * 2 + 1) * HF;

    sage_mfma<<<(NI + 127) / 128, 256, 0, stream>>>(agg_i, ci, bp0, bl0, ni, NI);
    sage_mfma<<<(NU + 127) / 128, 256, 0, stream>>>(agg_u, cu, bp1, bl1, nu, NU);

    cu = nu;
    ci = ni;
  }
}

// Round 5
// 1079.993 us; speedup vs baseline: 3.4072x; 1.2839x over previous
//
#include <hip/hip_runtime.h>

#define HF 128

typedef __attribute__((ext_vector_type(8))) short short8;
typedef __attribute__((ext_vector_type(16))) float f32x16;

__device__ inline unsigned short f2bf(float x) {
  unsigned u = __float_as_uint(x);
  unsigned r = u + 0x7fffu + ((u >> 16) & 1u);
  return (unsigned short)(r >> 16);
}

// split 8 fp32 -> bf16 hi (truncate) + bf16 lo (residual, RNE)
__device__ inline void split8(const float4 fa, const float4 fb, short8& hi, short8& lo)
{
  float f[8] = {fa.x, fa.y, fa.z, fa.w, fb.x, fb.y, fb.z, fb.w};
  union { unsigned int u[4]; short8 s; } H, L;
#pragma unroll
  for (int p = 0; p < 4; ++p) {
    unsigned u0 = __float_as_uint(f[2 * p]);
    unsigned u1 = __float_as_uint(f[2 * p + 1]);
    H.u[p] = (u0 >> 16) | (u1 & 0xffff0000u);
    float l0 = f[2 * p]     - __uint_as_float(u0 & 0xffff0000u);
    float l1 = f[2 * p + 1] - __uint_as_float(u1 & 0xffff0000u);
    L.u[p] = (unsigned)f2bf(l0) | ((unsigned)f2bf(l1) << 16);
  }
  hi = H.s; lo = L.s;
}

// ---------- input projection: out[N][128] = x[N][K] @ w[K][128] + b ----------
template<int K>
__global__ __launch_bounds__(256) void proj_kernel(
    const float* __restrict__ x, const float* __restrict__ w,
    const float* __restrict__ b, float* __restrict__ out, int N)
{
  __shared__ float w_s[K][HF];
  __shared__ float x_s[64][K];
  const int tid = threadIdx.x;
  const int r0 = blockIdx.x * 64;

  for (int idx = tid; idx < K * (HF / 4); idx += 256) {
    int k = idx >> 5, c4 = idx & 31;
    *(float4*)&w_s[k][c4 * 4] = *(const float4*)(w + (size_t)k * HF + c4 * 4);
  }
  for (int idx = tid; idx < 64 * (K / 4); idx += 256) {
    int r = idx / (K / 4), c4 = idx % (K / 4);
    int row = r0 + r;
    float4 v = {0.f, 0.f, 0.f, 0.f};
    if (row < N) v = *(const float4*)(x + (size_t)row * K + c4 * 4);
    *(float4*)&x_s[r][c4 * 4] = v;
  }
  __syncthreads();

  const int cg = tid & 31;
  const int rg = tid >> 5;
  const int jc = cg * 4;
  const float4 bv = *(const float4*)(b + jc);
  float acc[8][4];
#pragma unroll
  for (int rr = 0; rr < 8; ++rr) {
    acc[rr][0] = bv.x; acc[rr][1] = bv.y; acc[rr][2] = bv.z; acc[rr][3] = bv.w;
  }

  for (int k = 0; k < K; k += 4) {
    float4 wv[4];
#pragma unroll
    for (int t = 0; t < 4; ++t) wv[t] = *(const float4*)&w_s[k + t][jc];
#pragma unroll
    for (int rr = 0; rr < 8; ++rr) {
      const float4 x4 = *(const float4*)&x_s[rg * 8 + rr][k];
      float xa[4] = {x4.x, x4.y, x4.z, x4.w};
#pragma unroll
      for (int t = 0; t < 4; ++t) {
        acc[rr][0] = fmaf(xa[t], wv[t].x, acc[rr][0]);
        acc[rr][1] = fmaf(xa[t], wv[t].y, acc[rr][1]);
        acc[rr][2] = fmaf(xa[t], wv[t].z, acc[rr][2]);
        acc[rr][3] = fmaf(xa[t], wv[t].w, acc[rr][3]);
      }
    }
  }

#pragma unroll
  for (int rr = 0; rr < 8; ++rr) {
    int row = r0 + rg * 8 + rr;
    if (row < N) {
      float4 o = {acc[rr][0], acc[rr][1], acc[rr][2], acc[rr][3]};
      *(float4*)(out + (size_t)row * HF + jc) = o;
    }
  }
}

// ---------- CSR build ----------
__global__ void count_kernel(const int* __restrict__ dst, int* __restrict__ cnt,
                             int* __restrict__ pos, int E)
{
  int e = blockIdx.x * blockDim.x + threadIdx.x;
  if (e < E) pos[e] = atomicAdd(&cnt[dst[e]], 1);
}

__global__ __launch_bounds__(1024) void scan_p1(int* __restrict__ data, int* __restrict__ bsum, int n)
{
  __shared__ int s[1024];
  int tid = threadIdx.x;
  int i = blockIdx.x * 1024 + tid;
  int v = (i < n) ? data[i] : 0;
  s[tid] = v;
  __syncthreads();
  for (int off = 1; off < 1024; off <<= 1) {
    int t = (tid >= off) ? s[tid - off] : 0;
    __syncthreads();
    s[tid] += t;
    __syncthreads();
  }
  if (i < n) data[i] = s[tid] - v;
  if (tid == 1023) bsum[blockIdx.x] = s[1023];
}

__global__ __launch_bounds__(1024) void scan_p2(int* __restrict__ bsum, int nb)
{
  __shared__ int s[1024];
  int tid = threadIdx.x;
  int v = (tid < nb) ? bsum[tid] : 0;
  s[tid] = v;
  __syncthreads();
  for (int off = 1; off < 1024; off <<= 1) {
    int t = (tid >= off) ? s[tid - off] : 0;
    __syncthreads();
    s[tid] += t;
    __syncthreads();
  }
  if (tid < nb) bsum[tid] = s[tid] - v;
}

__global__ __launch_bounds__(1024) void scan_p3(int* __restrict__ data, const int* __restrict__ bsum,
                                                int n, int total)
{
  int i = blockIdx.x * 1024 + threadIdx.x;
  if (i < n) data[i] += bsum[blockIdx.x];
  if (i == 0) data[n] = total;
}

__global__ void fill_kernel(const int* __restrict__ dst, const int* __restrict__ src,
                            const int* __restrict__ rp, const int* __restrict__ pos,
                            int* __restrict__ colv, int E)
{
  int e = blockIdx.x * blockDim.x + threadIdx.x;
  if (e < E) colv[rp[dst[e]] + pos[e]] = src[e];
}

// ---------- mean aggregation v2: one wave per dst, 2 halves x 2-deep unroll ---
// lanes 0-31 take even edge slots, 32-63 odd; each lane reads float4 of the row.
// 4 independent gather chains in flight per wave (was ~1).
__global__ __launch_bounds__(256) void agg_kernel(
    const float* __restrict__ feat, const int* __restrict__ rp,
    const int* __restrict__ colv, float* __restrict__ out, int ndst)
{
  int gw = (int)((blockIdx.x * blockDim.x + threadIdx.x) >> 6);
  int lane = threadIdx.x & 63;
  int half = lane >> 5;
  int fi = (lane & 31) * 4;
  int nw = (int)((gridDim.x * blockDim.x) >> 6);
  for (int d = gw; d < ndst; d += nw) {
    int beg = rp[d], end = rp[d + 1];
    float4 a0 = {0.f, 0.f, 0.f, 0.f}, a1 = {0.f, 0.f, 0.f, 0.f};
    int j = beg + half;
    for (; j + 2 < end; j += 4) {
      int s0 = colv[j];
      int s1 = colv[j + 2];
      const float4 v0 = *(const float4*)(feat + (size_t)s0 * HF + fi);
      const float4 v1 = *(const float4*)(feat + (size_t)s1 * HF + fi);
      a0.x += v0.x; a0.y += v0.y; a0.z += v0.z; a0.w += v0.w;
      a1.x += v1.x; a1.y += v1.y; a1.z += v1.z; a1.w += v1.w;
    }
    for (; j < end; j += 2) {
      int s0 = colv[j];
      const float4 v0 = *(const float4*)(feat + (size_t)s0 * HF + fi);
      a0.x += v0.x; a0.y += v0.y; a0.z += v0.z; a0.w += v0.w;
    }
    float4 a;
    a.x = a0.x + a1.x; a.y = a0.y + a1.y; a.z = a0.z + a1.z; a.w = a0.w + a1.w;
    a.x += __shfl_xor(a.x, 32);
    a.y += __shfl_xor(a.y, 32);
    a.z += __shfl_xor(a.z, 32);
    a.w += __shfl_xor(a.w, 32);
    if (half == 0) {
      int dg = end - beg;
      float inv = 1.0f / (float)(dg > 0 ? dg : 1);
      float4 o = {a.x * inv, a.y * inv, a.z * inv, a.w * inv};
      *(float4*)(out + (size_t)d * HF + fi) = o;
    }
  }
}

// ---------- weight pack: W=[Wl;Wr] (256x128) -> bf16 hi/lo MFMA-frag tiles ----
// layout: bpack + combo*131072 + kc*16384 + part*8192 + kt*4096 + ct*1024 + lane*16
// frag (32x32x16 B operand): lane l: col = ct*32 + (l&31), k = kc*32+kt*16+(l>>5)*8+j
__global__ void wpack_kernel(const float* __restrict__ wl, const float* __restrict__ wr,
                             unsigned char* __restrict__ bpack, int ncombo)
{
  int t = blockIdx.x * 256 + threadIdx.x;
  int total = ncombo << 12;
  if (t >= total) return;
  int lane = t & 63;
  int ct = (t >> 6) & 3;
  int kt = (t >> 8) & 1;
  int kc = (t >> 9) & 7;
  int combo = t >> 12;
  const float* WL = wl + (size_t)combo * HF * HF;
  const float* WR = wr + (size_t)combo * HF * HF;
  int col = ct * 32 + (lane & 31);
  int kbase = kc * 32 + kt * 16 + (lane >> 5) * 8;
  float f[8];
#pragma unroll
  for (int j = 0; j < 8; ++j) {
    int k = kbase + j;
    f[j] = (k < HF) ? WL[(size_t)k * HF + col] : WR[(size_t)(k - HF) * HF + col];
  }
  unsigned int hi[4], lo[4];
#pragma unroll
  for (int p = 0; p < 4; ++p) {
    unsigned u0 = __float_as_uint(f[2 * p]);
    unsigned u1 = __float_as_uint(f[2 * p + 1]);
    hi[p] = (u0 >> 16) | (u1 & 0xffff0000u);
    float l0 = f[2 * p]     - __uint_as_float(u0 & 0xffff0000u);
    float l1 = f[2 * p + 1] - __uint_as_float(u1 & 0xffff0000u);
    lo[p] = (unsigned)f2bf(l0) | ((unsigned)f2bf(l1) << 16);
  }
  size_t base = (size_t)combo * 131072 + kc * 16384 + kt * 4096 + ct * 1024 + lane * 16;
  uint4 h = {hi[0], hi[1], hi[2], hi[3]};
  uint4 l = {lo[0], lo[1], lo[2], lo[3]};
  *(uint4*)(bpack + base) = h;
  *(uint4*)(bpack + base + 8192) = l;
}

// ---------- fused SAGE layer v3 (MFMA split-3, pipelined) ---------------------
// out = relu([agg|x] @ [Wl;Wr] + b). block 256 = 4 waves; tile 128x128;
// wave = 64x64 (2x2 32x32 tiles). K=256 in 8 chunks of 32.
// A: reg-staged + double-buffered LDS (2x16KB), XOR-swizzled; loads for chunk
// k+1 issued right after the (single) barrier, ds_write AFTER the MFMA phase
// so HBM latency hides under compute (T14). B: per-wave direct global->reg
// fragment loads (128KB pack is L2-resident; no LDS, no extra barrier).
__global__ __launch_bounds__(256) void sage_mfma(
    const float* __restrict__ agg, const float* __restrict__ x,
    const unsigned char* __restrict__ bpk, const float* __restrict__ bias,
    float* __restrict__ out, int N)
{
  __shared__ float4 a_s4[2][1024];       // 2 x 128 rows x 8 float4, swizzled
  const int tid = threadIdx.x;
  const int lane = tid & 63;
  const int w = tid >> 6;
  const int wr_ = w >> 1;                // wave row group -> rows wr_*64
  const int wc  = w & 1;                 // wave col group -> cols wc*64
  const int r0 = blockIdx.x * 128;

  float4 areg[4];

  f32x16 acc[2][2];
#pragma unroll
  for (int a = 0; a < 2; ++a)
#pragma unroll
    for (int b = 0; b < 2; ++b)
#pragma unroll
      for (int i = 0; i < 16; ++i) acc[a][b][i] = 0.f;

  // prologue: stage chunk 0
  {
    const int colbase = 0;
#pragma unroll
    for (int i = 0; i < 4; ++i) {
      int idx = i * 256 + tid;
      int r = idx >> 3, c = idx & 7;
      int grow = r0 + r;
      float4 v = {0.f, 0.f, 0.f, 0.f};
      if (grow < N) v = *(const float4*)(agg + (size_t)grow * HF + colbase + c * 4);
      areg[i] = v;
    }
#pragma unroll
    for (int i = 0; i < 4; ++i) {
      int idx = i * 256 + tid;
      int r = idx >> 3, c = idx & 7;
      a_s4[0][r * 8 + (c ^ (r & 7))] = areg[i];
    }
  }

  int cur = 0;
  for (int kc = 0; kc < 8; ++kc) {
    __syncthreads();  // A[cur] visible; all waves done reading A[cur^1]

    // issue next chunk's A loads (HBM) immediately — consumed only at tail
    if (kc < 7) {
      const float* srcp = (kc + 1 < 4) ? agg : x;
      const int colbase = ((kc + 1) & 3) * 32;
#pragma unroll
      for (int i = 0; i < 4; ++i) {
        int idx = i * 256 + tid;
        int r = idx >> 3, c = idx & 7;
        int grow = r0 + r;
        float4 v = {0.f, 0.f, 0.f, 0.f};
        if (grow < N) v = *(const float4*)(srcp + (size_t)grow * HF + colbase + c * 4);
        areg[i] = v;
      }
    }

    // B fragments: direct global->reg (L2-resident pack)
    const uint4* gb = (const uint4*)(bpk + (size_t)kc * 16384);
    union U { uint4 u; short8 s; } bhi[2][2], blo[2][2];  // [kt][ctl]
#pragma unroll
    for (int kt = 0; kt < 2; ++kt)
#pragma unroll
      for (int ctl = 0; ctl < 2; ++ctl) {
        int ct = wc * 2 + ctl;
        int fi = kt * 256 + ct * 64 + lane;
        bhi[kt][ctl].u = gb[fi];
        blo[kt][ctl].u = gb[512 + fi];
      }

#pragma unroll
    for (int kt = 0; kt < 2; ++kt) {
      short8 ahi[2], alo[2];
#pragma unroll
      for (int rt = 0; rt < 2; ++rt) {
        int row_l = wr_ * 64 + rt * 32 + (lane & 31);
        int c0 = kt * 4 + (lane >> 5) * 2;
        float4 fa = a_s4[cur][row_l * 8 + (c0 ^ (row_l & 7))];
        float4 fb = a_s4[cur][row_l * 8 + ((c0 + 1) ^ (row_l & 7))];
        split8(fa, fb, ahi[rt], alo[rt]);
      }
#pragma unroll
      for (int rt = 0; rt < 2; ++rt)
#pragma unroll
        for (int ctl = 0; ctl < 2; ++ctl) {
          acc[rt][ctl] = __builtin_amdgcn_mfma_f32_32x32x16_bf16(ahi[rt], bhi[kt][ctl].s, acc[rt][ctl], 0, 0, 0);
          acc[rt][ctl] = __builtin_amdgcn_mfma_f32_32x32x16_bf16(ahi[rt], blo[kt][ctl].s, acc[rt][ctl], 0, 0, 0);
          acc[rt][ctl] = __builtin_amdgcn_mfma_f32_32x32x16_bf16(alo[rt], bhi[kt][ctl].s, acc[rt][ctl], 0, 0, 0);
        }
    }

    // write next chunk into the other buffer (waits the remaining HBM latency
    // here, after compute, instead of at a barrier drain)
    if (kc < 7) {
#pragma unroll
      for (int i = 0; i < 4; ++i) {
        int idx = i * 256 + tid;
        int r = idx >> 3, c = idx & 7;
        a_s4[cur ^ 1][r * 8 + (c ^ (r & 7))] = areg[i];
      }
    }
    cur ^= 1;
  }

  // epilogue: bias + relu. C/D layout: col=lane&31, row=(reg&3)+8*(reg>>2)+4*(lane>>5)
#pragma unroll
  for (int ctl = 0; ctl < 2; ++ctl) {
    int gcol = wc * 64 + ctl * 32 + (lane & 31);
    float bv = bias[gcol];
#pragma unroll
    for (int rt = 0; rt < 2; ++rt) {
#pragma unroll
      for (int reg = 0; reg < 16; ++reg) {
        int row_l = (reg & 3) + 8 * (reg >> 2) + 4 * (lane >> 5);
        int grow = r0 + wr_ * 64 + rt * 32 + row_l;
        if (grow < N) {
          float v = acc[rt][ctl][reg] + bv;
          out[(size_t)grow * HF + gcol] = fmaxf(v, 0.f);
        }
      }
    }
  }
}

extern "C" void kernel_launch(void* const* d_in, const int* in_sizes, int n_in,
                              void* d_out, int out_size, void* d_ws, size_t ws_size,
                              hipStream_t stream)
{
  const float* x_user  = (const float*)d_in[0];
  const float* x_item  = (const float*)d_in[1];
  const float* user_w  = (const float*)d_in[2];
  const float* user_b  = (const float*)d_in[3];
  const float* item_w  = (const float*)d_in[4];
  const float* item_b  = (const float*)d_in[5];
  const float* conv_wl = (const float*)d_in[6];
  const float* conv_bl = (const float*)d_in[7];
  const float* conv_wr = (const float*)d_in[8];
  const int* src_u2i = (const int*)d_in[9];
  const int* dst_u2i = (const int*)d_in[10];
  const int* src_i2u = (const int*)d_in[11];
  const int* dst_i2u = (const int*)d_in[12];

  const int NU = in_sizes[0] / 32;
  const int NI = in_sizes[1] / 64;
  const int E  = in_sizes[9];
  const int L  = in_sizes[6] / (2 * HF * HF);

  float* out_u = (float*)d_out;
  float* out_i = out_u + (size_t)NU * HF;

  char* wsb = (char*)d_ws;
  size_t off = 0;
  auto alloc = [&](size_t bytes) -> void* {
    void* p = wsb + off;
    off = (off + bytes + 255) & ~(size_t)255;
    return p;
  };
  float* uA    = (float*)alloc((size_t)NU * HF * 4);
  float* iA    = (float*)alloc((size_t)NI * HF * 4);
  float* agg_u = (float*)alloc((size_t)NU * HF * 4);
  float* agg_i = (float*)alloc((size_t)NI * HF * 4);
  int* rp_i    = (int*)alloc((size_t)(NI + 1) * 4);
  int* rp_u    = (int*)alloc((size_t)(NU + 1) * 4);
  int* pos     = (int*)alloc((size_t)E * 4);
  int* col_u2i = (int*)alloc((size_t)E * 4);
  int* col_i2u = (int*)alloc((size_t)E * 4);
  int* bsum    = (int*)alloc(4096 * 4);
  unsigned char* bpack = (unsigned char*)alloc((size_t)(2 * L) * 131072);
  (void)ws_size; (void)n_in; (void)out_size;

  // 1) input projections (into d_out, consumed by layer 0)
  proj_kernel<32><<<(NU + 63) / 64, 256, 0, stream>>>(x_user, user_w, user_b, out_u, NU);
  proj_kernel<64><<<(NI + 63) / 64, 256, 0, stream>>>(x_item, item_w, item_b, out_i, NI);

  // 2) weight packing (once; 2L combos)
  {
    int total = (2 * L) << 12;
    wpack_kernel<<<(total + 255) / 256, 256, 0, stream>>>(conv_wl, conv_wr, bpack, 2 * L);
  }

  // 3) CSR build for both directions (graph reused across layers)
  auto build_csr = [&](const int* dst, const int* srcv, int* rp, int* colv, int n) {
    (void)hipMemsetAsync(rp, 0, (size_t)(n + 1) * sizeof(int), stream);
    int gE = (E + 255) / 256;
    count_kernel<<<gE, 256, 0, stream>>>(dst, rp, pos, E);
    int nb = (n + 1023) / 1024;
    scan_p1<<<nb, 1024, 0, stream>>>(rp, bsum, n);
    scan_p2<<<1, 1024, 0, stream>>>(bsum, nb);
    scan_p3<<<nb, 1024, 0, stream>>>(rp, bsum, n, E);
    fill_kernel<<<gE, 256, 0, stream>>>(dst, srcv, rp, pos, colv, E);
  };
  build_csr(dst_u2i, src_u2i, rp_i, col_u2i, NI);
  build_csr(dst_i2u, src_i2u, rp_u, col_i2u, NU);

  // 4) layers
  const float* cu = out_u;
  const float* ci = out_i;
  for (int l = 0; l < L; ++l) {
    float* nu = (l & 1) ? out_u : uA;
    float* ni = (l & 1) ? out_i : iA;

    agg_kernel<<<(NI + 3) / 4, 256, 0, stream>>>(cu, rp_i, col_u2i, agg_i, NI);
    agg_kernel<<<(NU + 3) / 4, 256, 0, stream>>>(ci, rp_u, col_i2u, agg_u, NU);

    const unsigned char* bp0 = bpack + (size_t)(l * 2 + 0) * 131072;
    const unsigned char* bp1 = bpack + (size_t)(l * 2 + 1) * 131072;
    const float* bl0 = conv_bl + (size_t)(l * 2 + 0) * HF;
    const float* bl1 = conv_bl + (size_t)(l * 2 + 1) * HF;

    sage_mfma<<<(NI + 127) / 128, 256, 0, stream>>>(agg_i, ci, bp0, bl0, ni, NI);
    sage_mfma<<<(NU + 127) / 128, 256, 0, stream>>>(agg_u, cu, bp1, bl1, nu, NU);

    cu = nu;
    ci = ni;
  }
}

// Round 6
// 1076.839 us; speedup vs baseline: 3.4172x; 1.0029x over previous
//
#include <hip/hip_runtime.h>

#define HF 128

typedef __attribute__((ext_vector_type(8))) short short8;
typedef __attribute__((ext_vector_type(16))) float f32x16;

__device__ inline unsigned short f2bf(float x) {
  unsigned u = __float_as_uint(x);
  unsigned r = u + 0x7fffu + ((u >> 16) & 1u);
  return (unsigned short)(r >> 16);
}

// split 8 fp32 -> bf16 hi (truncate) + bf16 lo (residual, RNE)
__device__ inline void split8(const float4 fa, const float4 fb, short8& hi, short8& lo)
{
  float f[8] = {fa.x, fa.y, fa.z, fa.w, fb.x, fb.y, fb.z, fb.w};
  union { unsigned int u[4]; short8 s; } H, L;
#pragma unroll
  for (int p = 0; p < 4; ++p) {
    unsigned u0 = __float_as_uint(f[2 * p]);
    unsigned u1 = __float_as_uint(f[2 * p + 1]);
    H.u[p] = (u0 >> 16) | (u1 & 0xffff0000u);
    float l0 = f[2 * p]     - __uint_as_float(u0 & 0xffff0000u);
    float l1 = f[2 * p + 1] - __uint_as_float(u1 & 0xffff0000u);
    L.u[p] = (unsigned)f2bf(l0) | ((unsigned)f2bf(l1) << 16);
  }
  hi = H.s; lo = L.s;
}

// ---------- input projection: out[N][128] = x[N][K] @ w[K][128] + b ----------
template<int K>
__global__ __launch_bounds__(256) void proj_kernel(
    const float* __restrict__ x, const float* __restrict__ w,
    const float* __restrict__ b, float* __restrict__ out, int N)
{
  __shared__ float w_s[K][HF];
  __shared__ float x_s[64][K];
  const int tid = threadIdx.x;
  const int r0 = blockIdx.x * 64;

  for (int idx = tid; idx < K * (HF / 4); idx += 256) {
    int k = idx >> 5, c4 = idx & 31;
    *(float4*)&w_s[k][c4 * 4] = *(const float4*)(w + (size_t)k * HF + c4 * 4);
  }
  for (int idx = tid; idx < 64 * (K / 4); idx += 256) {
    int r = idx / (K / 4), c4 = idx % (K / 4);
    int row = r0 + r;
    float4 v = {0.f, 0.f, 0.f, 0.f};
    if (row < N) v = *(const float4*)(x + (size_t)row * K + c4 * 4);
    *(float4*)&x_s[r][c4 * 4] = v;
  }
  __syncthreads();

  const int cg = tid & 31;
  const int rg = tid >> 5;
  const int jc = cg * 4;
  const float4 bv = *(const float4*)(b + jc);
  float acc[8][4];
#pragma unroll
  for (int rr = 0; rr < 8; ++rr) {
    acc[rr][0] = bv.x; acc[rr][1] = bv.y; acc[rr][2] = bv.z; acc[rr][3] = bv.w;
  }

  for (int k = 0; k < K; k += 4) {
    float4 wv[4];
#pragma unroll
    for (int t = 0; t < 4; ++t) wv[t] = *(const float4*)&w_s[k + t][jc];
#pragma unroll
    for (int rr = 0; rr < 8; ++rr) {
      const float4 x4 = *(const float4*)&x_s[rg * 8 + rr][k];
      float xa[4] = {x4.x, x4.y, x4.z, x4.w};
#pragma unroll
      for (int t = 0; t < 4; ++t) {
        acc[rr][0] = fmaf(xa[t], wv[t].x, acc[rr][0]);
        acc[rr][1] = fmaf(xa[t], wv[t].y, acc[rr][1]);
        acc[rr][2] = fmaf(xa[t], wv[t].z, acc[rr][2]);
        acc[rr][3] = fmaf(xa[t], wv[t].w, acc[rr][3]);
      }
    }
  }

#pragma unroll
  for (int rr = 0; rr < 8; ++rr) {
    int row = r0 + rg * 8 + rr;
    if (row < N) {
      float4 o = {acc[rr][0], acc[rr][1], acc[rr][2], acc[rr][3]};
      *(float4*)(out + (size_t)row * HF + jc) = o;
    }
  }
}

// ---------- CSR build ----------
__global__ void count_kernel(const int* __restrict__ dst, int* __restrict__ cnt,
                             int* __restrict__ pos, int E)
{
  int e = blockIdx.x * blockDim.x + threadIdx.x;
  if (e < E) pos[e] = atomicAdd(&cnt[dst[e]], 1);
}

__global__ __launch_bounds__(1024) void scan_p1(int* __restrict__ data, int* __restrict__ bsum, int n)
{
  __shared__ int s[1024];
  int tid = threadIdx.x;
  int i = blockIdx.x * 1024 + tid;
  int v = (i < n) ? data[i] : 0;
  s[tid] = v;
  __syncthreads();
  for (int off = 1; off < 1024; off <<= 1) {
    int t = (tid >= off) ? s[tid - off] : 0;
    __syncthreads();
    s[tid] += t;
    __syncthreads();
  }
  if (i < n) data[i] = s[tid] - v;
  if (tid == 1023) bsum[blockIdx.x] = s[1023];
}

__global__ __launch_bounds__(1024) void scan_p2(int* __restrict__ bsum, int nb)
{
  __shared__ int s[1024];
  int tid = threadIdx.x;
  int v = (tid < nb) ? bsum[tid] : 0;
  s[tid] = v;
  __syncthreads();
  for (int off = 1; off < 1024; off <<= 1) {
    int t = (tid >= off) ? s[tid - off] : 0;
    __syncthreads();
    s[tid] += t;
    __syncthreads();
  }
  if (tid < nb) bsum[tid] = s[tid] - v;
}

__global__ __launch_bounds__(1024) void scan_p3(int* __restrict__ data, const int* __restrict__ bsum,
                                                int n, int total)
{
  int i = blockIdx.x * 1024 + threadIdx.x;
  if (i < n) data[i] += bsum[blockIdx.x];
  if (i == 0) data[n] = total;
}

__global__ void fill_kernel(const int* __restrict__ dst, const int* __restrict__ src,
                            const int* __restrict__ rp, const int* __restrict__ pos,
                            int* __restrict__ colv, int E)
{
  int e = blockIdx.x * blockDim.x + threadIdx.x;
  if (e < E) colv[rp[dst[e]] + pos[e]] = src[e];
}

// ---------- mean aggregation v3: one wave per dst, 4x16-lane groups, 2-deep ---
// each 16-lane group reads a full 512B row (2 float4/lane); groups take edge
// slots j ≡ g (mod 4); 2-deep unroll -> 8 rows in flight per wave (was 4).
__global__ __launch_bounds__(256) void agg_kernel(
    const float* __restrict__ feat, const int* __restrict__ rp,
    const int* __restrict__ colv, float* __restrict__ out, int ndst)
{
  int gw = (int)((blockIdx.x * blockDim.x + threadIdx.x) >> 6);
  int lane = threadIdx.x & 63;
  int g = lane >> 4;
  int fi = (lane & 15) * 8;
  int nw = (int)((gridDim.x * blockDim.x) >> 6);
  for (int d = gw; d < ndst; d += nw) {
    int beg = rp[d], end = rp[d + 1];
    float4 a0a = {0.f,0.f,0.f,0.f}, a0b = {0.f,0.f,0.f,0.f};
    float4 a1a = {0.f,0.f,0.f,0.f}, a1b = {0.f,0.f,0.f,0.f};
    int j = beg + g;
    for (; j + 4 < end; j += 8) {
      int s0 = colv[j];
      int s1 = colv[j + 4];
      const float4 v0a = *(const float4*)(feat + (size_t)s0 * HF + fi);
      const float4 v0b = *(const float4*)(feat + (size_t)s0 * HF + fi + 4);
      const float4 v1a = *(const float4*)(feat + (size_t)s1 * HF + fi);
      const float4 v1b = *(const float4*)(feat + (size_t)s1 * HF + fi + 4);
      a0a.x += v0a.x; a0a.y += v0a.y; a0a.z += v0a.z; a0a.w += v0a.w;
      a0b.x += v0b.x; a0b.y += v0b.y; a0b.z += v0b.z; a0b.w += v0b.w;
      a1a.x += v1a.x; a1a.y += v1a.y; a1a.z += v1a.z; a1a.w += v1a.w;
      a1b.x += v1b.x; a1b.y += v1b.y; a1b.z += v1b.z; a1b.w += v1b.w;
    }
    for (; j < end; j += 4) {
      int s0 = colv[j];
      const float4 v0a = *(const float4*)(feat + (size_t)s0 * HF + fi);
      const float4 v0b = *(const float4*)(feat + (size_t)s0 * HF + fi + 4);
      a0a.x += v0a.x; a0a.y += v0a.y; a0a.z += v0a.z; a0a.w += v0a.w;
      a0b.x += v0b.x; a0b.y += v0b.y; a0b.z += v0b.z; a0b.w += v0b.w;
    }
    float4 sa, sb;
    sa.x = a0a.x + a1a.x; sa.y = a0a.y + a1a.y; sa.z = a0a.z + a1a.z; sa.w = a0a.w + a1a.w;
    sb.x = a0b.x + a1b.x; sb.y = a0b.y + a1b.y; sb.z = a0b.z + a1b.z; sb.w = a0b.w + a1b.w;
    sa.x += __shfl_xor(sa.x, 16); sa.y += __shfl_xor(sa.y, 16);
    sa.z += __shfl_xor(sa.z, 16); sa.w += __shfl_xor(sa.w, 16);
    sb.x += __shfl_xor(sb.x, 16); sb.y += __shfl_xor(sb.y, 16);
    sb.z += __shfl_xor(sb.z, 16); sb.w += __shfl_xor(sb.w, 16);
    sa.x += __shfl_xor(sa.x, 32); sa.y += __shfl_xor(sa.y, 32);
    sa.z += __shfl_xor(sa.z, 32); sa.w += __shfl_xor(sa.w, 32);
    sb.x += __shfl_xor(sb.x, 32); sb.y += __shfl_xor(sb.y, 32);
    sb.z += __shfl_xor(sb.z, 32); sb.w += __shfl_xor(sb.w, 32);
    if (g == 0) {
      int dg = end - beg;
      float inv = 1.0f / (float)(dg > 0 ? dg : 1);
      float4 oa = {sa.x * inv, sa.y * inv, sa.z * inv, sa.w * inv};
      float4 ob = {sb.x * inv, sb.y * inv, sb.z * inv, sb.w * inv};
      *(float4*)(out + (size_t)d * HF + fi) = oa;
      *(float4*)(out + (size_t)d * HF + fi + 4) = ob;
    }
  }
}

// ---------- weight pack: W=[Wl;Wr] (256x128) -> bf16 hi/lo MFMA-frag tiles ----
// layout: bpack + combo*131072 + kc*16384 + part*8192 + kt*4096 + ct*1024 + lane*16
// frag (32x32x16 B operand): lane l: col = ct*32 + (l&31), k = kc*32+kt*16+(l>>5)*8+j
__global__ void wpack_kernel(const float* __restrict__ wl, const float* __restrict__ wr,
                             unsigned char* __restrict__ bpack, int ncombo)
{
  int t = blockIdx.x * 256 + threadIdx.x;
  int total = ncombo << 12;
  if (t >= total) return;
  int lane = t & 63;
  int ct = (t >> 6) & 3;
  int kt = (t >> 8) & 1;
  int kc = (t >> 9) & 7;
  int combo = t >> 12;
  const float* WL = wl + (size_t)combo * HF * HF;
  const float* WR = wr + (size_t)combo * HF * HF;
  int col = ct * 32 + (lane & 31);
  int kbase = kc * 32 + kt * 16 + (lane >> 5) * 8;
  float f[8];
#pragma unroll
  for (int j = 0; j < 8; ++j) {
    int k = kbase + j;
    f[j] = (k < HF) ? WL[(size_t)k * HF + col] : WR[(size_t)(k - HF) * HF + col];
  }
  unsigned int hi[4], lo[4];
#pragma unroll
  for (int p = 0; p < 4; ++p) {
    unsigned u0 = __float_as_uint(f[2 * p]);
    unsigned u1 = __float_as_uint(f[2 * p + 1]);
    hi[p] = (u0 >> 16) | (u1 & 0xffff0000u);
    float l0 = f[2 * p]     - __uint_as_float(u0 & 0xffff0000u);
    float l1 = f[2 * p + 1] - __uint_as_float(u1 & 0xffff0000u);
    lo[p] = (unsigned)f2bf(l0) | ((unsigned)f2bf(l1) << 16);
  }
  size_t base = (size_t)combo * 131072 + kc * 16384 + kt * 4096 + ct * 1024 + lane * 16;
  uint4 h = {hi[0], hi[1], hi[2], hi[3]};
  uint4 l = {lo[0], lo[1], lo[2], lo[3]};
  *(uint4*)(bpack + base) = h;
  *(uint4*)(bpack + base + 8192) = l;
}

// ---------- fused SAGE layer v4 (MFMA split-3, A+B both pipelined) ------------
// Per chunk the compute phase waits on NOTHING fresh from global: A for chunk
// k+1 is prefetched to regs (ds_write after compute), B for chunk k+1 is
// prefetched to a second named reg set (rule #20: no runtime-indexed reg
// arrays -> pair-loop with static B0/B1 and static LDS buffer indices).
union BU { uint4 u; short8 s; };
struct BF { BU h[2][2]; BU l[2][2]; };   // [kt][ctl]

__device__ __forceinline__ void loadB(const unsigned char* __restrict__ bpk, int c,
                                      int wc, int lane, BF& B)
{
  const uint4* gb = (const uint4*)(bpk + (size_t)c * 16384);
#pragma unroll
  for (int kt = 0; kt < 2; ++kt)
#pragma unroll
    for (int ctl = 0; ctl < 2; ++ctl) {
      int fi = kt * 256 + (wc * 2 + ctl) * 64 + lane;
      B.h[kt][ctl].u = gb[fi];
      B.l[kt][ctl].u = gb[512 + fi];
    }
}

__device__ __forceinline__ void loadA(const float* __restrict__ srcp, int colbase,
                                      int r0, int tid, int N, float4 (&areg)[4])
{
#pragma unroll
  for (int i = 0; i < 4; ++i) {
    int idx = i * 256 + tid;
    int r = idx >> 3, cc = idx & 7;
    int grow = r0 + r;
    float4 v = {0.f, 0.f, 0.f, 0.f};
    if (grow < N) v = *(const float4*)(srcp + (size_t)grow * HF + colbase + cc * 4);
    areg[i] = v;
  }
}

__device__ __forceinline__ void writeA(float4 (&As)[1024], int tid, const float4 (&areg)[4])
{
#pragma unroll
  for (int i = 0; i < 4; ++i) {
    int idx = i * 256 + tid;
    int r = idx >> 3, cc = idx & 7;
    As[r * 8 + (cc ^ (r & 7))] = areg[i];
  }
}

__device__ __forceinline__ void computeChunk(const float4 (&As)[1024], int wr_, int lane,
                                             const BF& B, f32x16 (&acc)[2][2])
{
#pragma unroll
  for (int kt = 0; kt < 2; ++kt) {
    short8 ahi[2], alo[2];
#pragma unroll
    for (int rt = 0; rt < 2; ++rt) {
      int row_l = wr_ * 64 + rt * 32 + (lane & 31);
      int c0 = kt * 4 + (lane >> 5) * 2;
      float4 fa = As[row_l * 8 + (c0 ^ (row_l & 7))];
      float4 fb = As[row_l * 8 + ((c0 + 1) ^ (row_l & 7))];
      split8(fa, fb, ahi[rt], alo[rt]);
    }
#pragma unroll
    for (int rt = 0; rt < 2; ++rt)
#pragma unroll
      for (int ctl = 0; ctl < 2; ++ctl) {
        acc[rt][ctl] = __builtin_amdgcn_mfma_f32_32x32x16_bf16(ahi[rt], B.h[kt][ctl].s, acc[rt][ctl], 0, 0, 0);
        acc[rt][ctl] = __builtin_amdgcn_mfma_f32_32x32x16_bf16(ahi[rt], B.l[kt][ctl].s, acc[rt][ctl], 0, 0, 0);
        acc[rt][ctl] = __builtin_amdgcn_mfma_f32_32x32x16_bf16(alo[rt], B.h[kt][ctl].s, acc[rt][ctl], 0, 0, 0);
      }
  }
}

__global__ __launch_bounds__(256) void sage_mfma(
    const float* __restrict__ agg, const float* __restrict__ x,
    const unsigned char* __restrict__ bpk, const float* __restrict__ bias,
    float* __restrict__ out, int N)
{
  __shared__ float4 a_s4[2][1024];       // 2 x (128 rows x 8 float4), swizzled
  const int tid = threadIdx.x;
  const int lane = tid & 63;
  const int w = tid >> 6;
  const int wr_ = w >> 1;                // wave row group -> rows wr_*64
  const int wc  = w & 1;                 // wave col group -> cols wc*64
  const int r0 = blockIdx.x * 128;

  float4 areg[4];
  BF B0, B1;

  f32x16 acc[2][2];
#pragma unroll
  for (int a = 0; a < 2; ++a)
#pragma unroll
    for (int b = 0; b < 2; ++b)
#pragma unroll
      for (int i = 0; i < 16; ++i) acc[a][b][i] = 0.f;

  // prologue: chunk 0 -> LDS[0], B0 regs
  loadA(agg, 0, r0, tid, N, areg);
  writeA(a_s4[0], tid, areg);
  loadB(bpk, 0, wc, lane, B0);

  for (int p = 0; p < 4; ++p) {
    const int ca = 2 * p;                // even chunk, lives in LDS[0], uses B0
    __syncthreads();
    {
      const float* srcp = (ca + 1 < 4) ? agg : x;
      loadA(srcp, ((ca + 1) & 3) * 32, r0, tid, N, areg);
      loadB(bpk, ca + 1, wc, lane, B1);
    }
    computeChunk(a_s4[0], wr_, lane, B0, acc);
    writeA(a_s4[1], tid, areg);

    const int cb = 2 * p + 1;            // odd chunk, LDS[1], B1
    __syncthreads();
    if (cb < 7) {
      const float* srcp = (cb + 1 < 4) ? agg : x;
      loadA(srcp, ((cb + 1) & 3) * 32, r0, tid, N, areg);
      loadB(bpk, cb + 1, wc, lane, B0);
    }
    computeChunk(a_s4[1], wr_, lane, B1, acc);
    if (cb < 7) writeA(a_s4[0], tid, areg);
  }

  // epilogue: bias + relu. C/D layout: col=lane&31, row=(reg&3)+8*(reg>>2)+4*(lane>>5)
#pragma unroll
  for (int ctl = 0; ctl < 2; ++ctl) {
    int gcol = wc * 64 + ctl * 32 + (lane & 31);
    float bv = bias[gcol];
#pragma unroll
    for (int rt = 0; rt < 2; ++rt) {
#pragma unroll
      for (int reg = 0; reg < 16; ++reg) {
        int row_l = (reg & 3) + 8 * (reg >> 2) + 4 * (lane >> 5);
        int grow = r0 + wr_ * 64 + rt * 32 + row_l;
        if (grow < N) {
          float v = acc[rt][ctl][reg] + bv;
          out[(size_t)grow * HF + gcol] = fmaxf(v, 0.f);
        }
      }
    }
  }
}

extern "C" void kernel_launch(void* const* d_in, const int* in_sizes, int n_in,
                              void* d_out, int out_size, void* d_ws, size_t ws_size,
                              hipStream_t stream)
{
  const float* x_user  = (const float*)d_in[0];
  const float* x_item  = (const float*)d_in[1];
  const float* user_w  = (const float*)d_in[2];
  const float* user_b  = (const float*)d_in[3];
  const float* item_w  = (const float*)d_in[4];
  const float* item_b  = (const float*)d_in[5];
  const float* conv_wl = (const float*)d_in[6];
  const float* conv_bl = (const float*)d_in[7];
  const float* conv_wr = (const float*)d_in[8];
  const int* src_u2i = (const int*)d_in[9];
  const int* dst_u2i = (const int*)d_in[10];
  const int* src_i2u = (const int*)d_in[11];
  const int* dst_i2u = (const int*)d_in[12];

  const int NU = in_sizes[0] / 32;
  const int NI = in_sizes[1] / 64;
  const int E  = in_sizes[9];
  const int L  = in_sizes[6] / (2 * HF * HF);

  float* out_u = (float*)d_out;
  float* out_i = out_u + (size_t)NU * HF;

  char* wsb = (char*)d_ws;
  size_t off = 0;
  auto alloc = [&](size_t bytes) -> void* {
    void* p = wsb + off;
    off = (off + bytes + 255) & ~(size_t)255;
    return p;
  };
  float* uA    = (float*)alloc((size_t)NU * HF * 4);
  float* iA    = (float*)alloc((size_t)NI * HF * 4);
  float* agg_u = (float*)alloc((size_t)NU * HF * 4);
  float* agg_i = (float*)alloc((size_t)NI * HF * 4);
  int* rp_i    = (int*)alloc((size_t)(NI + 1) * 4);
  int* rp_u    = (int*)alloc((size_t)(NU + 1) * 4);
  int* pos     = (int*)alloc((size_t)E * 4);
  int* col_u2i = (int*)alloc((size_t)E * 4);
  int* col_i2u = (int*)alloc((size_t)E * 4);
  int* bsum    = (int*)alloc(4096 * 4);
  unsigned char* bpack = (unsigned char*)alloc((size_t)(2 * L) * 131072);
  (void)ws_size; (void)n_in; (void)out_size;

  // 1) input projections (into d_out, consumed by layer 0)
  proj_kernel<32><<<(NU + 63) / 64, 256, 0, stream>>>(x_user, user_w, user_b, out_u, NU);
  proj_kernel<64><<<(NI + 63) / 64, 256, 0, stream>>>(x_item, item_w, item_b, out_i, NI);

  // 2) weight packing (once; 2L combos)
  {
    int total = (2 * L) << 12;
    wpack_kernel<<<(total + 255) / 256, 256, 0, stream>>>(conv_wl, conv_wr, bpack, 2 * L);
  }

  // 3) CSR build for both directions (graph reused across layers)
  auto build_csr = [&](const int* dst, const int* srcv, int* rp, int* colv, int n) {
    (void)hipMemsetAsync(rp, 0, (size_t)(n + 1) * sizeof(int), stream);
    int gE = (E + 255) / 256;
    count_kernel<<<gE, 256, 0, stream>>>(dst, rp, pos, E);
    int nb = (n + 1023) / 1024;
    scan_p1<<<nb, 1024, 0, stream>>>(rp, bsum, n);
    scan_p2<<<1, 1024, 0, stream>>>(bsum, nb);
    scan_p3<<<nb, 1024, 0, stream>>>(rp, bsum, n, E);
    fill_kernel<<<gE, 256, 0, stream>>>(dst, srcv, rp, pos, colv, E);
  };
  build_csr(dst_u2i, src_u2i, rp_i, col_u2i, NI);
  build_csr(dst_i2u, src_i2u, rp_u, col_i2u, NU);

  // 4) layers
  const float* cu = out_u;
  const float* ci = out_i;
  for (int l = 0; l < L; ++l) {
    float* nu = (l & 1) ? out_u : uA;
    float* ni = (l & 1) ? out_i : iA;

    agg_kernel<<<(NI + 3) / 4, 256, 0, stream>>>(cu, rp_i, col_u2i, agg_i, NI);
    agg_kernel<<<(NU + 3) / 4, 256, 0, stream>>>(ci, rp_u, col_i2u, agg_u, NU);

    const unsigned char* bp0 = bpack + (size_t)(l * 2 + 0) * 131072;
    const unsigned char* bp1 = bpack + (size_t)(l * 2 + 1) * 131072;
    const float* bl0 = conv_bl + (size_t)(l * 2 + 0) * HF;
    const float* bl1 = conv_bl + (size_t)(l * 2 + 1) * HF;

    sage_mfma<<<(NI + 127) / 128, 256, 0, stream>>>(agg_i, ci, bp0, bl0, ni, NI);
    sage_mfma<<<(NU + 127) / 128, 256, 0, stream>>>(agg_u, cu, bp1, bl1, nu, NU);

    cu = nu;
    ci = ni;
  }
}